// Round 6
// baseline (295.928 us; speedup 1.0000x reference)
//
#include <hip/hip_runtime.h>
#include <hip/hip_bf16.h>

// Graph Actor Model — R5:
//  - mega kernel: adjacency->edges (nontemporal) || weight packing || encoder MLP
//    (encoder device code reused verbatim from R2, which passed correctness)
//  - tail GEMMs: barrier-free K (R4), windows shrunk to 32 KB for occupancy
//  - prop: 8-deep unrolled gather

#define NN   8192
#define EPAD 128

#define BUILD_BLOCKS 2048
#define PACK_BLOCKS  8
#define ENC_BLOCKS   256
#define MEGA_GRID (BUILD_BLOCKS + PACK_BLOCKS + ENC_BLOCKS)

typedef __attribute__((ext_vector_type(8))) short bf16x8;
typedef __attribute__((ext_vector_type(4))) float f32x4;
typedef __attribute__((ext_vector_type(4))) unsigned uint32x4;

// image byte offsets (all 4KB-aligned); tile = BN*128 bytes
#define IMG_GCN 81920u
#define IMG_GD  344064u
#define IMG_P1  606208u
#define IMG_P2  868352u
#define IMG_PI  933888u

// ---------- split-bf16 helpers ----------

__device__ __forceinline__ unsigned f32_to_split(float v) {
    unsigned b = __builtin_bit_cast(unsigned, v);
    unsigned hi = (b + 0x7fffu + ((b >> 16) & 1u)) & 0xffff0000u;
    float lo = v - __builtin_bit_cast(float, hi);
    unsigned lb = __builtin_bit_cast(unsigned, lo);
    unsigned lo16 = (lb + 0x7fffu + ((lb >> 16) & 1u)) >> 16;
    return hi | lo16;
}

__device__ __forceinline__ void unpack_frags(const uint4& q0, const uint4& q1,
                                             bf16x8& hi, bf16x8& lo) {
    union { unsigned u[4]; bf16x8 v; } H, L;
    H.u[0] = (q0.y & 0xffff0000u) | (q0.x >> 16);
    H.u[1] = (q0.w & 0xffff0000u) | (q0.z >> 16);
    H.u[2] = (q1.y & 0xffff0000u) | (q1.x >> 16);
    H.u[3] = (q1.w & 0xffff0000u) | (q1.z >> 16);
    L.u[0] = (q0.y << 16) | (q0.x & 0xffffu);
    L.u[1] = (q0.w << 16) | (q0.z & 0xffffu);
    L.u[2] = (q1.y << 16) | (q1.x & 0xffffu);
    L.u[3] = (q1.w << 16) | (q1.z & 0xffffu);
    hi = H.v; lo = L.v;
}

__device__ __forceinline__ void split2(float v, unsigned short& h, unsigned short& l) {
    unsigned b = __builtin_bit_cast(unsigned, v);
    unsigned hr = (b + 0x7fffu + ((b >> 16) & 1u)) & 0xffff0000u;
    h = (unsigned short)(hr >> 16);
    float lo = v - __builtin_bit_cast(float, hr);
    unsigned lb = __builtin_bit_cast(unsigned, lo);
    l = (unsigned short)((lb + 0x7fffu + ((lb >> 16) & 1u)) >> 16);
}

__device__ __forceinline__ void splitfrag(const float4& v0, const float4& v1,
                                          bf16x8& ah, bf16x8& al) {
    union { unsigned short us[8]; bf16x8 v; } H, L;
    float vv[8] = {v0.x, v0.y, v0.z, v0.w, v1.x, v1.y, v1.z, v1.w};
    #pragma unroll
    for (int j = 0; j < 8; ++j) {
        unsigned short h, l;
        split2(vv[j], h, l);
        H.us[j] = h; L.us[j] = l;
    }
    ah = H.v; al = L.v;
}

__device__ __forceinline__ void gload_lds16(const void* g, void* l) {
    typedef const __attribute__((address_space(1))) unsigned int GU;
    typedef __attribute__((address_space(3))) unsigned int LU;
    __builtin_amdgcn_global_load_lds((GU*)g, (LU*)l, 16, 0, 0);
}

// ---------- mega partition 1: edge build (nontemporal stream) ----------

__device__ void build_part(const uint32x4* adj4, int* cnt, int* edges, int bid) {
    const size_t total = (size_t)NN * NN / 4;
    const size_t stride = (size_t)BUILD_BLOCKS * 512;
    for (size_t i = (size_t)bid * 512 + threadIdx.x; i < total; i += stride) {
        uint32x4 v = __builtin_nontemporal_load(&adj4[i]);
        if ((v.x | v.y | v.z | v.w) != 0u) {
            size_t base = i * 4;
            int r  = (int)(base / NN);
            int c0 = (int)(base % NN);
            #pragma unroll
            for (int j = 0; j < 4; ++j) {
                if (v[j] != 0u) {
                    int c = c0 + j;
                    int slot = atomicAdd(&cnt[c], 1);
                    if (slot < EPAD) edges[(size_t)c * EPAD + slot] = r;
                }
            }
        }
    }
}

// ---------- mega partition 2: weight image packing ----------
// tile (nh,ks): cols n in [0,BN), bytes n*128 + ((c ^ (n&7))<<4); tile idx = nh*nks+ks.

__device__ void pack_layer(const float* W, int NOUT, int K, int BN_,
                           unsigned imgoff, int rank, int nblk,
                           unsigned char* img) {
    const int nks = K / 32;
    const int total = (NOUT / BN_) * nks * BN_ * 8;   // chunks
    const int tileb = BN_ * 128;
    for (int u = rank * 512 + threadIdx.x; u < total; u += nblk * 512) {
        int tile = u / (BN_ * 8);
        int rem  = u - tile * (BN_ * 8);
        int n    = rem >> 3;
        int c    = rem & 7;
        int nh   = tile / nks;
        int ks   = tile - nh * nks;
        int col  = nh * BN_ + n;
        int kb   = ks * 32 + c * 4;
        uint4 q;
        q.x = f32_to_split(W[(size_t)(kb + 0) * NOUT + col]);
        q.y = f32_to_split(W[(size_t)(kb + 1) * NOUT + col]);
        q.z = f32_to_split(W[(size_t)(kb + 2) * NOUT + col]);
        q.w = f32_to_split(W[(size_t)(kb + 3) * NOUT + col]);
        *(uint4*)(img + imgoff + (size_t)tile * tileb + n * 128 + ((c ^ (n & 7)) << 4)) = q;
    }
}

// ---------- mega partition 3: encoder (verbatim from R2, which passed) ----------

__device__ void enc_stage(const float* W, int NOUT, int col0, int NT, int k0,
                          unsigned char* bufB) {
    for (int u = threadIdx.x; u < NT * 8; u += 512) {
        int n = u >> 3, c = u & 7;
        unsigned short h[4], l[4];
        #pragma unroll
        for (int j = 0; j < 4; ++j) {
            float w = W[(size_t)(k0 + c * 4 + j) * NOUT + col0 + n];
            split2(w, h[j], l[j]);
        }
        uint2 hv, lv;
        hv.x = (unsigned)h[0] | ((unsigned)h[1] << 16);
        hv.y = (unsigned)h[2] | ((unsigned)h[3] << 16);
        lv.x = (unsigned)l[0] | ((unsigned)l[1] << 16);
        lv.y = (unsigned)l[2] | ((unsigned)l[3] << 16);
        *(uint2*)(bufB + n * 80 + c * 8) = hv;
        *(uint2*)(bufB + NT * 80 + n * 80 + c * 8) = lv;
    }
}

__device__ void enc_part(const float* feat,
                         const float* We1, const float* be1,
                         const float* We2, const float* be2,
                         float* Hs, float* X, int bid, unsigned char* bufB) {
    const int t = threadIdx.x, lane = t & 63, wave = t >> 6;
    const int wr = wave >> 2, wc = wave & 3, lm = lane & 15, lk = lane >> 4;
    const int r0 = bid * 32;

    // GEMM1: T1 = relu(F @ We1 + b) -> Hs cols 0..63 (stride 256)
    const float* frow = feat + (size_t)(r0 + wr * 16 + lm) * 64 + lk * 8;
    float4 fa0[2], fa1[2];
    #pragma unroll
    for (int ks = 0; ks < 2; ++ks) {
        fa0[ks] = *(const float4*)(frow + ks * 32);
        fa1[ks] = *(const float4*)(frow + ks * 32 + 4);
    }
    f32x4 acc0 = {0.f,0.f,0.f,0.f}, acc1 = {0.f,0.f,0.f,0.f};
    #pragma unroll
    for (int ks = 0; ks < 2; ++ks) {
        enc_stage(We1, 64, 0, 64, ks * 32, bufB);
        __syncthreads();
        if (wc < 2) {
            bf16x8 ah, al; splitfrag(fa0[ks], fa1[ks], ah, al);
            int n0 = wc * 32 + lm;
            bf16x8 bh0 = *(const bf16x8*)(bufB + n0 * 80 + lk * 16);
            bf16x8 bl0 = *(const bf16x8*)(bufB + 5120 + n0 * 80 + lk * 16);
            bf16x8 bh1 = *(const bf16x8*)(bufB + (n0 + 16) * 80 + lk * 16);
            bf16x8 bl1 = *(const bf16x8*)(bufB + 5120 + (n0 + 16) * 80 + lk * 16);
            acc0 = __builtin_amdgcn_mfma_f32_16x16x32_bf16(ah, bh0, acc0, 0, 0, 0);
            acc0 = __builtin_amdgcn_mfma_f32_16x16x32_bf16(ah, bl0, acc0, 0, 0, 0);
            acc0 = __builtin_amdgcn_mfma_f32_16x16x32_bf16(al, bh0, acc0, 0, 0, 0);
            acc1 = __builtin_amdgcn_mfma_f32_16x16x32_bf16(ah, bh1, acc1, 0, 0, 0);
            acc1 = __builtin_amdgcn_mfma_f32_16x16x32_bf16(ah, bl1, acc1, 0, 0, 0);
            acc1 = __builtin_amdgcn_mfma_f32_16x16x32_bf16(al, bh1, acc1, 0, 0, 0);
        }
        __syncthreads();
    }
    if (wc < 2) {
        #pragma unroll
        for (int fn = 0; fn < 2; ++fn) {
            int col = wc * 32 + fn * 16 + lm;
            float b = be1[col];
            f32x4 a = fn ? acc1 : acc0;
            #pragma unroll
            for (int q = 0; q < 4; ++q) {
                int row = r0 + wr * 16 + lk * 4 + q;
                Hs[(size_t)row * 256 + col] = fmaxf(a[q] + b, 0.f);
            }
        }
    }
    __threadfence();
    __syncthreads();

    // GEMM2: X = relu(T1 @ We2 + b), N=256 in two halves
    const float* hrow = Hs + (size_t)(r0 + wr * 16 + lm) * 256 + lk * 8;
    float4 ha0[2], ha1[2];
    #pragma unroll
    for (int ks = 0; ks < 2; ++ks) {
        ha0[ks] = *(const float4*)(hrow + ks * 32);
        ha1[ks] = *(const float4*)(hrow + ks * 32 + 4);
    }
    #pragma unroll
    for (int nh = 0; nh < 2; ++nh) {
        f32x4 c0 = {0.f,0.f,0.f,0.f}, c1 = {0.f,0.f,0.f,0.f};
        #pragma unroll
        for (int ks = 0; ks < 2; ++ks) {
            enc_stage(We2, 256, nh * 128, 128, ks * 32, bufB);
            __syncthreads();
            bf16x8 ah, al; splitfrag(ha0[ks], ha1[ks], ah, al);
            int n0 = wc * 32 + lm;
            bf16x8 bh0 = *(const bf16x8*)(bufB + n0 * 80 + lk * 16);
            bf16x8 bl0 = *(const bf16x8*)(bufB + 10240 + n0 * 80 + lk * 16);
            bf16x8 bh1 = *(const bf16x8*)(bufB + (n0 + 16) * 80 + lk * 16);
            bf16x8 bl1 = *(const bf16x8*)(bufB + 10240 + (n0 + 16) * 80 + lk * 16);
            c0 = __builtin_amdgcn_mfma_f32_16x16x32_bf16(ah, bh0, c0, 0, 0, 0);
            c0 = __builtin_amdgcn_mfma_f32_16x16x32_bf16(ah, bl0, c0, 0, 0, 0);
            c0 = __builtin_amdgcn_mfma_f32_16x16x32_bf16(al, bh0, c0, 0, 0, 0);
            c1 = __builtin_amdgcn_mfma_f32_16x16x32_bf16(ah, bh1, c1, 0, 0, 0);
            c1 = __builtin_amdgcn_mfma_f32_16x16x32_bf16(ah, bl1, c1, 0, 0, 0);
            c1 = __builtin_amdgcn_mfma_f32_16x16x32_bf16(al, bh1, c1, 0, 0, 0);
            __syncthreads();
        }
        #pragma unroll
        for (int fn = 0; fn < 2; ++fn) {
            int colg = nh * 128 + wc * 32 + fn * 16 + lm;
            float b = be2[colg];
            f32x4 a = fn ? c1 : c0;
            #pragma unroll
            for (int q = 0; q < 4; ++q) {
                int row = r0 + wr * 16 + lk * 4 + q;
                X[(size_t)row * 256 + colg] = fmaxf(a[q] + b, 0.f);
            }
        }
    }
}

// ---------- mega kernel ----------

__global__ __launch_bounds__(512) void mega_kernel(
    const uint32x4* adj4, int* cnt, int* edges,
    const float* feat,
    const float* We1, const float* be1, const float* We2, const float* be2,
    const float* Wgcn, const float* Wgd, const float* Wp1, const float* Wp2,
    const float* Wpi,
    float* Hs, float* X, unsigned char* img)
{
    __shared__ unsigned char bufB[20480];
    int bid = blockIdx.x;
    if (bid < BUILD_BLOCKS) {
        build_part(adj4, cnt, edges, bid);
    } else if (bid < BUILD_BLOCKS + PACK_BLOCKS) {
        int pb = bid - BUILD_BLOCKS;
        if (pb < 2)      pack_layer(Wgcn, 256, 256, 64, IMG_GCN, pb,     2, img);
        else if (pb < 4) pack_layer(Wgd,  256, 256, 64, IMG_GD,  pb - 2, 2, img);
        else if (pb < 6) pack_layer(Wp1,  128, 512, 64, IMG_P1,  pb - 4, 2, img);
        else if (pb < 7) pack_layer(Wp2,  128, 128, 64, IMG_P2,  0,      1, img);
        else             pack_layer(Wpi,   32, 128, 32, IMG_PI,  0,      1, img);
    } else {
        enc_part(feat, We1, be1, We2, be2, Hs, X,
                 bid - BUILD_BLOCKS - PACK_BLOCKS, bufB);
    }
}

// ---------- sparse propagation: 2 nodes/block, float2, 8-deep ----------

__global__ __launch_bounds__(256) void prop_kernel(
    const float* __restrict__ h, const int* __restrict__ cnt,
    const int* __restrict__ edges, float* __restrict__ out)
{
    __shared__ int   se[2][EPAD];
    __shared__ float sd[2][EPAD];
    const int half = threadIdx.x >> 7;
    const int tl   = threadIdx.x & 127;
    const int c = blockIdx.x * 2 + half;
    int n = cnt[c]; if (n > EPAD) n = EPAD;
    if (tl < n) {
        int r = edges[(size_t)c * EPAD + tl];
        se[half][tl] = r;
        int dr = cnt[r];
        sd[half][tl] = dr > 0 ? rsqrtf((float)dr) : 0.f;
    }
    __syncthreads();
    float2 a[8];
    #pragma unroll
    for (int j = 0; j < 8; ++j) { a[j].x = 0.f; a[j].y = 0.f; }
    int i = 0;
    for (; i + 8 <= n; i += 8) {
        #pragma unroll
        for (int j = 0; j < 8; ++j) {
            float2 v = *(const float2*)&h[(size_t)se[half][i + j] * 256 + tl * 2];
            float s = sd[half][i + j];
            a[j].x += s * v.x; a[j].y += s * v.y;
        }
    }
    for (; i < n; ++i) {
        float2 v = *(const float2*)&h[(size_t)se[half][i] * 256 + tl * 2];
        float s = sd[half][i];
        a[0].x += s * v.x; a[0].y += s * v.y;
    }
    int dc = cnt[c];
    float di = dc > 0 ? rsqrtf((float)dc) : 0.f;
    float2 r2;
    r2.x = di * (((a[0].x + a[1].x) + (a[2].x + a[3].x)) + ((a[4].x + a[5].x) + (a[6].x + a[7].x)));
    r2.y = di * (((a[0].y + a[1].y) + (a[2].y + a[3].y)) + ((a[4].y + a[5].y) + (a[6].y + a[7].y)));
    *(float2*)&out[(size_t)c * 256 + tl * 2] = r2;
}

// ---------- barrier-free-K MFMA GEMM (R4, windows shrunk to 4 tiles) ----------

template<int K1, int K2, int NOUT, int BN, bool RELU, bool MASK>
__global__ __launch_bounds__(256) void gemm3(
    const float* __restrict__ A1, const float* __restrict__ A2,
    const unsigned char* __restrict__ img, const float* __restrict__ bias,
    float* __restrict__ C, const float* __restrict__ maskv)
{
    constexpr int K      = K1 + K2;
    constexpr int NKS    = K / 32;
    constexpr int TILEB  = BN * 128;
    constexpr int WTILES = NKS > 4 ? 4 : NKS;   // 32 KB max LDS window
    constexpr int NWIN   = NKS / WTILES;
    constexpr int WN     = BN / 2;
    constexpr int FN     = WN / 16;
    constexpr int NCHUNK = WTILES * TILEB / 1024;

    __shared__ unsigned char Bs[WTILES * TILEB];

    const int t    = threadIdx.x;
    const int lane = t & 63;
    const int wave = t >> 6;
    const int wr   = wave >> 1;
    const int wc   = wave & 1;
    const int lm   = lane & 15;
    const int lk   = lane >> 4;
    const int row0 = blockIdx.x * 64;
    const int col0 = blockIdx.y * BN;
    const unsigned char* imgp = img + (size_t)blockIdx.y * NKS * TILEB;

    f32x4 acc[2][FN];
    #pragma unroll
    for (int i = 0; i < 2; ++i)
        #pragma unroll
        for (int j = 0; j < FN; ++j) {
            acc[i][j][0] = 0.f; acc[i][j][1] = 0.f;
            acc[i][j][2] = 0.f; acc[i][j][3] = 0.f;
        }

    #pragma unroll
    for (int w = 0; w < NWIN; ++w) {
        if (w > 0) __syncthreads();
        #pragma unroll
        for (int i = wave; i < NCHUNK; i += 4)
            gload_lds16(imgp + (size_t)w * WTILES * TILEB + (size_t)i * 1024 + lane * 16,
                        Bs + (size_t)i * 1024);
        __syncthreads();

        #pragma unroll
        for (int kl = 0; kl < WTILES; ++kl) {
            const int ks = w * WTILES + kl;
            const int kg = ks * 32 + lk * 8;
            bf16x8 bh[FN], bl[FN];
            #pragma unroll
            for (int fn = 0; fn < FN; ++fn) {
                int n = wc * WN + fn * 16 + lm;
                const unsigned char* bb = Bs + kl * TILEB + n * 128;
                uint4 q0 = *(const uint4*)(bb + (((lk * 2 + 0) ^ (n & 7)) << 4));
                uint4 q1 = *(const uint4*)(bb + (((lk * 2 + 1) ^ (n & 7)) << 4));
                unpack_frags(q0, q1, bh[fn], bl[fn]);
            }
            #pragma unroll
            for (int fm = 0; fm < 2; ++fm) {
                int m = row0 + wr * 32 + fm * 16 + lm;
                const float* ap; int kk = kg;
                if constexpr (K2 > 0) {
                    if (kg < K1) { ap = A1 + (size_t)m * K1; }
                    else         { ap = A2 + (size_t)m * K2; kk = kg - K1; }
                } else {
                    ap = A1 + (size_t)m * K1;
                }
                float4 v0 = *(const float4*)(ap + kk);
                float4 v1 = *(const float4*)(ap + kk + 4);
                bf16x8 ah, al;
                splitfrag(v0, v1, ah, al);
                #pragma unroll
                for (int fn = 0; fn < FN; ++fn) {
                    acc[fm][fn] = __builtin_amdgcn_mfma_f32_16x16x32_bf16(ah, bh[fn], acc[fm][fn], 0, 0, 0);
                    acc[fm][fn] = __builtin_amdgcn_mfma_f32_16x16x32_bf16(ah, bl[fn], acc[fm][fn], 0, 0, 0);
                    acc[fm][fn] = __builtin_amdgcn_mfma_f32_16x16x32_bf16(al, bh[fn], acc[fm][fn], 0, 0, 0);
                }
            }
        }
    }

    #pragma unroll
    for (int fm = 0; fm < 2; ++fm) {
        #pragma unroll
        for (int fn = 0; fn < FN; ++fn) {
            int col = col0 + wc * WN + fn * 16 + lm;
            float b = bias[col];
            #pragma unroll
            for (int q = 0; q < 4; ++q) {
                int row = row0 + wr * 32 + fm * 16 + lk * 4 + q;
                float v = acc[fm][fn][q] + b;
                if (RELU) v = fmaxf(v, 0.f);
                if (MASK) v *= maskv[row];
                C[(size_t)row * NOUT + col] = v;
            }
        }
    }
}

// ---------- launch ----------

extern "C" void kernel_launch(void* const* d_in, const int* in_sizes, int n_in,
                              void* d_out, int out_size, void* d_ws, size_t ws_size,
                              hipStream_t stream) {
    const float* features = (const float*)d_in[0];
    const float* adj      = (const float*)d_in[1];
    const float* mask     = (const float*)d_in[2];
    const float* W_e1  = (const float*)d_in[3];
    const float* b_e1  = (const float*)d_in[4];
    const float* W_e2  = (const float*)d_in[5];
    const float* b_e2  = (const float*)d_in[6];
    const float* W_gcn = (const float*)d_in[7];
    const float* b_gcn = (const float*)d_in[8];
    const float* W_gd  = (const float*)d_in[9];
    const float* b_gd  = (const float*)d_in[10];
    const float* W_p1  = (const float*)d_in[11];
    const float* b_p1  = (const float*)d_in[12];
    const float* W_p2  = (const float*)d_in[13];
    const float* b_p2  = (const float*)d_in[14];
    const float* W_pi  = (const float*)d_in[15];
    const float* b_pi  = (const float*)d_in[16];
    float* out = (float*)d_out;

    float* ws = (float*)d_ws;
    float* X  = ws;                                  // [NN,256]
    float* T  = X + (size_t)NN * 256;                // [NN,256]
    float* Hs = T + (size_t)NN * 256;                // [NN,256]
    int* cnt   = (int*)(Hs + (size_t)NN * 256);      // [NN]
    int* edges = cnt + NN;                           // [NN][EPAD]
    unsigned char* img = (unsigned char*)(edges + (size_t)NN * EPAD);

    hipMemsetAsync(cnt, 0, NN * sizeof(int), stream);

    // adjacency->edges (HBM floor) || weight packing || encoder MLP
    mega_kernel<<<MEGA_GRID, 512, 0, stream>>>(
        (const uint32x4*)adj, cnt, edges, features,
        W_e1, b_e1, W_e2, b_e2, W_gcn, W_gd, W_p1, W_p2, W_pi,
        Hs, X, img);

    // SGConv K=2
    prop_kernel<<<NN / 2, 256, 0, stream>>>(X, cnt, edges, T);
    prop_kernel<<<NN / 2, 256, 0, stream>>>(T, cnt, edges, Hs);

    // Xg = relu(Hs@Wgcn+b) -> T ; Xg2 = relu(T@Wgd+b) -> Hs
    gemm3<256, 0, 256, 64, true, false>
        <<<dim3(NN / 64, 4), 256, 0, stream>>>(Hs, nullptr, img + IMG_GCN, b_gcn, T, nullptr);
    gemm3<256, 0, 256, 64, true, false>
        <<<dim3(NN / 64, 4), 256, 0, stream>>>(T, nullptr, img + IMG_GD, b_gd, Hs, nullptr);

    // P1 = relu([Xg2|X]@Wp1+b) -> T ; P2 = relu(P1@Wp2+b) -> Hs
    gemm3<256, 256, 128, 64, true, false>
        <<<dim3(NN / 64, 2), 256, 0, stream>>>(Hs, X, img + IMG_P1, b_p1, T, nullptr);
    gemm3<128, 0, 128, 64, true, false>
        <<<dim3(NN / 64, 2), 256, 0, stream>>>(T, nullptr, img + IMG_P2, b_p2, Hs, nullptr);

    // pi = (P2@Wpi+b)*mask -> out
    gemm3<128, 0, 32, 32, false, true>
        <<<dim3(NN / 64, 1), 256, 0, stream>>>(Hs, nullptr, img + IMG_PI, b_pi, out, mask);
}

// Round 7
// 193.933 us; speedup vs baseline: 1.5259x; 1.5259x over previous
//
#include <hip/hip_runtime.h>
#include <hip/hip_bf16.h>

// Graph Actor Model — R6: R4 separate-kernel structure + latency-fixed build.
//  - build: 256-thr, no LDS, 8 independent uint4 loads in flight per thread
//    (R5 profile: build was latency-bound at 853 GB/s, 2.5 waves/SIMD)
//  - weight packing rides in the same dispatch (blocks >= BUILD_BLOCKS)
//  - GEMMs: barrier-free K windows (32 KB), split-bf16 MFMA (R4/R5 proven)
//  - prop: float2, 2 nodes/block, 8-deep unrolled gather (R5 proven)

#define NN   8192
#define EPAD 128
#define BUILD_BLOCKS 2048
#define PACK_BLOCKS  8

typedef __attribute__((ext_vector_type(8))) short bf16x8;
typedef __attribute__((ext_vector_type(4))) float f32x4;

// image byte offsets (4KB-aligned); tile = BN*128 bytes
#define IMG_E1  0u
#define IMG_E2  16384u
#define IMG_GCN 81920u
#define IMG_GD  344064u
#define IMG_P1  606208u
#define IMG_P2  868352u
#define IMG_PI  933888u

// ---------- split-bf16 helpers ----------

__device__ __forceinline__ unsigned f32_to_split(float v) {
    unsigned b = __builtin_bit_cast(unsigned, v);
    unsigned hi = (b + 0x7fffu + ((b >> 16) & 1u)) & 0xffff0000u;
    float lo = v - __builtin_bit_cast(float, hi);
    unsigned lb = __builtin_bit_cast(unsigned, lo);
    unsigned lo16 = (lb + 0x7fffu + ((lb >> 16) & 1u)) >> 16;
    return hi | lo16;
}

__device__ __forceinline__ void unpack_frags(const uint4& q0, const uint4& q1,
                                             bf16x8& hi, bf16x8& lo) {
    union { unsigned u[4]; bf16x8 v; } H, L;
    H.u[0] = (q0.y & 0xffff0000u) | (q0.x >> 16);
    H.u[1] = (q0.w & 0xffff0000u) | (q0.z >> 16);
    H.u[2] = (q1.y & 0xffff0000u) | (q1.x >> 16);
    H.u[3] = (q1.w & 0xffff0000u) | (q1.z >> 16);
    L.u[0] = (q0.y << 16) | (q0.x & 0xffffu);
    L.u[1] = (q0.w << 16) | (q0.z & 0xffffu);
    L.u[2] = (q1.y << 16) | (q1.x & 0xffffu);
    L.u[3] = (q1.w << 16) | (q1.z & 0xffffu);
    hi = H.v; lo = L.v;
}

__device__ __forceinline__ void split2(float v, unsigned short& h, unsigned short& l) {
    unsigned b = __builtin_bit_cast(unsigned, v);
    unsigned hr = (b + 0x7fffu + ((b >> 16) & 1u)) & 0xffff0000u;
    h = (unsigned short)(hr >> 16);
    float lo = v - __builtin_bit_cast(float, hr);
    unsigned lb = __builtin_bit_cast(unsigned, lo);
    l = (unsigned short)((lb + 0x7fffu + ((lb >> 16) & 1u)) >> 16);
}

__device__ __forceinline__ void splitfrag(const float4& v0, const float4& v1,
                                          bf16x8& ah, bf16x8& al) {
    union { unsigned short us[8]; bf16x8 v; } H, L;
    float vv[8] = {v0.x, v0.y, v0.z, v0.w, v1.x, v1.y, v1.z, v1.w};
    #pragma unroll
    for (int j = 0; j < 8; ++j) {
        unsigned short h, l;
        split2(vv[j], h, l);
        H.us[j] = h; L.us[j] = l;
    }
    ah = H.v; al = L.v;
}

__device__ __forceinline__ void gload_lds16(const void* g, void* l) {
    typedef const __attribute__((address_space(1))) unsigned int GU;
    typedef __attribute__((address_space(3))) unsigned int LU;
    __builtin_amdgcn_global_load_lds((GU*)g, (LU*)l, 16, 0, 0);
}

// ---------- build: 8 independent loads in flight ----------

__device__ __forceinline__ void handle_chunk(const uint4& v, size_t chunk,
                                             int* cnt, int* edges) {
    if ((v.x | v.y | v.z | v.w) != 0u) {
        size_t base = chunk * 4;
        int r  = (int)(base / NN);
        int c0 = (int)(base % NN);
        unsigned e[4] = {v.x, v.y, v.z, v.w};
        #pragma unroll
        for (int j = 0; j < 4; ++j) {
            if (e[j] != 0u) {
                int c = c0 + j;
                int slot = atomicAdd(&cnt[c], 1);
                if (slot < EPAD) edges[(size_t)c * EPAD + slot] = r;
            }
        }
    }
}

__device__ void build_part(const uint4* __restrict__ adj4,
                           int* __restrict__ cnt, int* __restrict__ edges,
                           int bid) {
    const size_t NT = (size_t)BUILD_BLOCKS * 256;          // 524288 threads
    // total chunks = NN*NN/4 = 16777216 = 32 per thread = 4 batches of 8
    size_t tid = (size_t)bid * 256 + threadIdx.x;
    #pragma unroll
    for (int b = 0; b < 4; ++b) {
        size_t i0 = tid + (size_t)(b * 8) * NT;
        uint4 v0 = adj4[i0 + 0 * NT];
        uint4 v1 = adj4[i0 + 1 * NT];
        uint4 v2 = adj4[i0 + 2 * NT];
        uint4 v3 = adj4[i0 + 3 * NT];
        uint4 v4 = adj4[i0 + 4 * NT];
        uint4 v5 = adj4[i0 + 5 * NT];
        uint4 v6 = adj4[i0 + 6 * NT];
        uint4 v7 = adj4[i0 + 7 * NT];
        handle_chunk(v0, i0 + 0 * NT, cnt, edges);
        handle_chunk(v1, i0 + 1 * NT, cnt, edges);
        handle_chunk(v2, i0 + 2 * NT, cnt, edges);
        handle_chunk(v3, i0 + 3 * NT, cnt, edges);
        handle_chunk(v4, i0 + 4 * NT, cnt, edges);
        handle_chunk(v5, i0 + 5 * NT, cnt, edges);
        handle_chunk(v6, i0 + 6 * NT, cnt, edges);
        handle_chunk(v7, i0 + 7 * NT, cnt, edges);
    }
}

// ---------- weight image packing ----------
// tile (nh,ks): cols n in [0,BN), bytes n*128 + ((c ^ (n&7))<<4); tile idx = nh*nks+ks.

__device__ void pack_layer(const float* W, int NOUT, int K, int BN_,
                           unsigned imgoff, int rank, int nblk,
                           unsigned char* img) {
    const int nks = K / 32;
    const int total = (NOUT / BN_) * nks * BN_ * 8;   // chunks
    const int tileb = BN_ * 128;
    for (int u = rank * 256 + threadIdx.x; u < total; u += nblk * 256) {
        int tile = u / (BN_ * 8);
        int rem  = u - tile * (BN_ * 8);
        int n    = rem >> 3;
        int c    = rem & 7;
        int nh   = tile / nks;
        int ks   = tile - nh * nks;
        int col  = nh * BN_ + n;
        int kb   = ks * 32 + c * 4;
        uint4 q;
        q.x = f32_to_split(W[(size_t)(kb + 0) * NOUT + col]);
        q.y = f32_to_split(W[(size_t)(kb + 1) * NOUT + col]);
        q.z = f32_to_split(W[(size_t)(kb + 2) * NOUT + col]);
        q.w = f32_to_split(W[(size_t)(kb + 3) * NOUT + col]);
        *(uint4*)(img + imgoff + (size_t)tile * tileb + n * 128 + ((c ^ (n & 7)) << 4)) = q;
    }
}

__global__ __launch_bounds__(256) void buildpack_kernel(
    const uint4* adj4, int* cnt, int* edges,
    const float* We1, const float* We2, const float* Wgcn, const float* Wgd,
    const float* Wp1, const float* Wp2, const float* Wpi, unsigned char* img)
{
    int bid = blockIdx.x;
    if (bid < BUILD_BLOCKS) {
        build_part(adj4, cnt, edges, bid);
    } else {
        int pb = bid - BUILD_BLOCKS;
        if (pb < 2)      pack_layer(Wgcn, 256, 256, 64, IMG_GCN, pb,     2, img);
        else if (pb < 4) pack_layer(Wgd,  256, 256, 64, IMG_GD,  pb - 2, 2, img);
        else if (pb < 6) pack_layer(Wp1,  128, 512, 64, IMG_P1,  pb - 4, 2, img);
        else if (pb < 7) { pack_layer(We2, 256,  64, 64, IMG_E2, 0, 1, img);
                           pack_layer(Wp2, 128, 128, 64, IMG_P2, 0, 1, img); }
        else             { pack_layer(We1,  64,  64, 64, IMG_E1, 0, 1, img);
                           pack_layer(Wpi,  32, 128, 32, IMG_PI, 0, 1, img); }
    }
}

// ---------- sparse propagation: 2 nodes/block, float2, 8-deep ----------

__global__ __launch_bounds__(256) void prop_kernel(
    const float* __restrict__ h, const int* __restrict__ cnt,
    const int* __restrict__ edges, float* __restrict__ out)
{
    __shared__ int   se[2][EPAD];
    __shared__ float sd[2][EPAD];
    const int half = threadIdx.x >> 7;
    const int tl   = threadIdx.x & 127;
    const int c = blockIdx.x * 2 + half;
    int n = cnt[c]; if (n > EPAD) n = EPAD;
    if (tl < n) {
        int r = edges[(size_t)c * EPAD + tl];
        se[half][tl] = r;
        int dr = cnt[r];
        sd[half][tl] = dr > 0 ? rsqrtf((float)dr) : 0.f;
    }
    __syncthreads();
    float2 a[8];
    #pragma unroll
    for (int j = 0; j < 8; ++j) { a[j].x = 0.f; a[j].y = 0.f; }
    int i = 0;
    for (; i + 8 <= n; i += 8) {
        #pragma unroll
        for (int j = 0; j < 8; ++j) {
            float2 v = *(const float2*)&h[(size_t)se[half][i + j] * 256 + tl * 2];
            float s = sd[half][i + j];
            a[j].x += s * v.x; a[j].y += s * v.y;
        }
    }
    for (; i < n; ++i) {
        float2 v = *(const float2*)&h[(size_t)se[half][i] * 256 + tl * 2];
        float s = sd[half][i];
        a[0].x += s * v.x; a[0].y += s * v.y;
    }
    int dc = cnt[c];
    float di = dc > 0 ? rsqrtf((float)dc) : 0.f;
    float2 r2;
    r2.x = di * (((a[0].x + a[1].x) + (a[2].x + a[3].x)) + ((a[4].x + a[5].x) + (a[6].x + a[7].x)));
    r2.y = di * (((a[0].y + a[1].y) + (a[2].y + a[3].y)) + ((a[4].y + a[5].y) + (a[6].y + a[7].y)));
    *(float2*)&out[(size_t)c * 256 + tl * 2] = r2;
}

// ---------- barrier-free-K MFMA GEMM (32 KB windows) ----------

template<int K1, int K2, int NOUT, int BN, bool RELU, bool MASK>
__global__ __launch_bounds__(256) void gemm3(
    const float* __restrict__ A1, const float* __restrict__ A2,
    const unsigned char* __restrict__ img, const float* __restrict__ bias,
    float* __restrict__ C, const float* __restrict__ maskv)
{
    constexpr int K      = K1 + K2;
    constexpr int NKS    = K / 32;
    constexpr int TILEB  = BN * 128;
    constexpr int WTILES = NKS > 4 ? 4 : NKS;   // 32 KB max LDS window
    constexpr int NWIN   = NKS / WTILES;
    constexpr int WN     = BN / 2;
    constexpr int FN     = WN / 16;
    constexpr int NCHUNK = WTILES * TILEB / 1024;

    __shared__ unsigned char Bs[WTILES * TILEB];

    const int t    = threadIdx.x;
    const int lane = t & 63;
    const int wave = t >> 6;
    const int wr   = wave >> 1;
    const int wc   = wave & 1;
    const int lm   = lane & 15;
    const int lk   = lane >> 4;
    const int row0 = blockIdx.x * 64;
    const int col0 = blockIdx.y * BN;
    const unsigned char* imgp = img + (size_t)blockIdx.y * NKS * TILEB;

    f32x4 acc[2][FN];
    #pragma unroll
    for (int i = 0; i < 2; ++i)
        #pragma unroll
        for (int j = 0; j < FN; ++j) {
            acc[i][j][0] = 0.f; acc[i][j][1] = 0.f;
            acc[i][j][2] = 0.f; acc[i][j][3] = 0.f;
        }

    #pragma unroll
    for (int w = 0; w < NWIN; ++w) {
        if (w > 0) __syncthreads();
        #pragma unroll
        for (int i = wave; i < NCHUNK; i += 4)
            gload_lds16(imgp + (size_t)w * WTILES * TILEB + (size_t)i * 1024 + lane * 16,
                        Bs + (size_t)i * 1024);
        __syncthreads();

        #pragma unroll
        for (int kl = 0; kl < WTILES; ++kl) {
            const int ks = w * WTILES + kl;
            const int kg = ks * 32 + lk * 8;
            bf16x8 bh[FN], bl[FN];
            #pragma unroll
            for (int fn = 0; fn < FN; ++fn) {
                int n = wc * WN + fn * 16 + lm;
                const unsigned char* bb = Bs + kl * TILEB + n * 128;
                uint4 q0 = *(const uint4*)(bb + (((lk * 2 + 0) ^ (n & 7)) << 4));
                uint4 q1 = *(const uint4*)(bb + (((lk * 2 + 1) ^ (n & 7)) << 4));
                unpack_frags(q0, q1, bh[fn], bl[fn]);
            }
            #pragma unroll
            for (int fm = 0; fm < 2; ++fm) {
                int m = row0 + wr * 32 + fm * 16 + lm;
                const float* ap; int kk = kg;
                if constexpr (K2 > 0) {
                    if (kg < K1) { ap = A1 + (size_t)m * K1; }
                    else         { ap = A2 + (size_t)m * K2; kk = kg - K1; }
                } else {
                    ap = A1 + (size_t)m * K1;
                }
                float4 v0 = *(const float4*)(ap + kk);
                float4 v1 = *(const float4*)(ap + kk + 4);
                bf16x8 ah, al;
                splitfrag(v0, v1, ah, al);
                #pragma unroll
                for (int fn = 0; fn < FN; ++fn) {
                    acc[fm][fn] = __builtin_amdgcn_mfma_f32_16x16x32_bf16(ah, bh[fn], acc[fm][fn], 0, 0, 0);
                    acc[fm][fn] = __builtin_amdgcn_mfma_f32_16x16x32_bf16(ah, bl[fn], acc[fm][fn], 0, 0, 0);
                    acc[fm][fn] = __builtin_amdgcn_mfma_f32_16x16x32_bf16(al, bh[fn], acc[fm][fn], 0, 0, 0);
                }
            }
        }
    }

    #pragma unroll
    for (int fm = 0; fm < 2; ++fm) {
        #pragma unroll
        for (int fn = 0; fn < FN; ++fn) {
            int col = col0 + wc * WN + fn * 16 + lm;
            float b = bias[col];
            #pragma unroll
            for (int q = 0; q < 4; ++q) {
                int row = row0 + wr * 32 + fm * 16 + lk * 4 + q;
                float v = acc[fm][fn][q] + b;
                if (RELU) v = fmaxf(v, 0.f);
                if (MASK) v *= maskv[row];
                C[(size_t)row * NOUT + col] = v;
            }
        }
    }
}

// ---------- launch ----------

extern "C" void kernel_launch(void* const* d_in, const int* in_sizes, int n_in,
                              void* d_out, int out_size, void* d_ws, size_t ws_size,
                              hipStream_t stream) {
    const float* features = (const float*)d_in[0];
    const float* adj      = (const float*)d_in[1];
    const float* mask     = (const float*)d_in[2];
    const float* W_e1  = (const float*)d_in[3];
    const float* b_e1  = (const float*)d_in[4];
    const float* W_e2  = (const float*)d_in[5];
    const float* b_e2  = (const float*)d_in[6];
    const float* W_gcn = (const float*)d_in[7];
    const float* b_gcn = (const float*)d_in[8];
    const float* W_gd  = (const float*)d_in[9];
    const float* b_gd  = (const float*)d_in[10];
    const float* W_p1  = (const float*)d_in[11];
    const float* b_p1  = (const float*)d_in[12];
    const float* W_p2  = (const float*)d_in[13];
    const float* b_p2  = (const float*)d_in[14];
    const float* W_pi  = (const float*)d_in[15];
    const float* b_pi  = (const float*)d_in[16];
    float* out = (float*)d_out;

    float* ws = (float*)d_ws;
    float* X  = ws;                                  // [NN,256]
    float* T  = X + (size_t)NN * 256;                // [NN,256]
    float* Hs = T + (size_t)NN * 256;                // [NN,256]
    int* cnt   = (int*)(Hs + (size_t)NN * 256);      // [NN]
    int* edges = cnt + NN;                           // [NN][EPAD]
    unsigned char* img = (unsigned char*)(edges + (size_t)NN * EPAD);

    hipMemsetAsync(cnt, 0, NN * sizeof(int), stream);

    // edge list (8-deep load pipeline) || weight-image packing
    buildpack_kernel<<<BUILD_BLOCKS + PACK_BLOCKS, 256, 0, stream>>>(
        (const uint4*)adj, cnt, edges,
        W_e1, W_e2, W_gcn, W_gd, W_p1, W_p2, W_pi, img);

    // encoder: T = relu(F@We1+b), X = relu(T@We2+b)
    gemm3<64, 0, 64, 64, true, false>
        <<<dim3(NN / 64, 1), 256, 0, stream>>>(features, nullptr, img + IMG_E1, b_e1, T, nullptr);
    gemm3<64, 0, 256, 64, true, false>
        <<<dim3(NN / 64, 4), 256, 0, stream>>>(T, nullptr, img + IMG_E2, b_e2, X, nullptr);

    // SGConv K=2
    prop_kernel<<<NN / 2, 256, 0, stream>>>(X, cnt, edges, T);
    prop_kernel<<<NN / 2, 256, 0, stream>>>(T, cnt, edges, Hs);

    // Xg = relu(Hs@Wgcn+b) -> T ; Xg2 = relu(T@Wgd+b) -> Hs
    gemm3<256, 0, 256, 64, true, false>
        <<<dim3(NN / 64, 4), 256, 0, stream>>>(Hs, nullptr, img + IMG_GCN, b_gcn, T, nullptr);
    gemm3<256, 0, 256, 64, true, false>
        <<<dim3(NN / 64, 4), 256, 0, stream>>>(T, nullptr, img + IMG_GD, b_gd, Hs, nullptr);

    // P1 = relu([Xg2|X]@Wp1+b) -> T ; P2 = relu(P1@Wp2+b) -> Hs
    gemm3<256, 256, 128, 64, true, false>
        <<<dim3(NN / 64, 2), 256, 0, stream>>>(Hs, X, img + IMG_P1, b_p1, T, nullptr);
    gemm3<128, 0, 128, 64, true, false>
        <<<dim3(NN / 64, 2), 256, 0, stream>>>(T, nullptr, img + IMG_P2, b_p2, Hs, nullptr);

    // pi = (P2@Wpi+b)*mask -> out
    gemm3<128, 0, 32, 32, false, true>
        <<<dim3(NN / 64, 1), 256, 0, stream>>>(Hs, nullptr, img + IMG_PI, b_pi, out, mask);
}